// Round 3
// baseline (502.246 us; speedup 1.0000x reference)
//
#include <hip/hip_runtime.h>

typedef float v2f __attribute__((ext_vector_type(2)));
typedef float v4f __attribute__((ext_vector_type(4)));

#define HH 512
#define WW 512
#define NPLANES 96        // 32 * 3
#define BLOCK 64          // 1 wave per block
#define COLS_PB 128       // 64 threads x 2 columns
#define ROWS_PB 64
#define COL_TILES 4       // 512 / 128
#define ROW_TILES 8       // 512 / 64
#define HALO 5
#define KW 11
#define PADL 8            // left pad (8 floats) so float4 global chunks stay aligned
#define LDSW 144          // 8 + 128 + 8
#define NGRP 5            // 5 full groups of 11 output rows = 55
#define NREM 9            // + 9 remainder rows = 64

#define C1V 1e-4f
#define C2V 9e-4f
#define EPSV 1e-8f
#define NPIX 25165824.0f  // 32*3*512*512

// per-thread ring: horizontal-blur results for 11 rows x 2 columns
struct Rings { v2f hx[KW], hy[KW], hx2[KW], hy2[KW], hxy[KW]; };

struct Staged { v4f g0, g1; int a, c40, c41; };

// Issue the global loads for one replacement row (both arrays interleaved by
// lane parity). float4 chunks are 16B aligned (PADL=8, C0 % 4 == 0) and are
// always fully inside or fully outside the image -> chunk-level zeroing.
__device__ __forceinline__ Staged stage_issue(const float* __restrict__ xp,
                                              const float* __restrict__ yp,
                                              int C0, int ri, int t)
{
  Staged st;
  st.a = t & 1;
  st.c40 = t >> 1;            // chunks 0..31
  st.c41 = 32 + (t >> 1);     // chunks 32..35 (lanes 0..7 only)
  st.g0 = (v4f){0.f, 0.f, 0.f, 0.f};
  st.g1 = (v4f){0.f, 0.f, 0.f, 0.f};
  const bool rok = (ri >= 0) && (ri < HH);
  const float* grow = (st.a ? yp : xp) + (ptrdiff_t)ri * WW;
  const int gc0 = C0 - PADL + 4 * st.c40;
  if (rok && gc0 >= 0 && gc0 < WW) st.g0 = *(const v4f*)(grow + gc0);
  const int gc1 = C0 - PADL + 4 * st.c41;
  if (t < 8 && rok && gc1 >= 0 && gc1 < WW) st.g1 = *(const v4f*)(grow + gc1);
  return st;
}

__device__ __forceinline__ void stage_commit(float (*lds)[2][LDSW], int slot,
                                             const Staged& st, int t)
{
  *(v4f*)&lds[slot][st.a][4 * st.c40] = st.g0;
  if (t < 8) *(v4f*)&lds[slot][st.a][4 * st.c41] = st.g1;
}

// horizontal 11-tap blur for thread t's 2-column pair from LDS slot S.
// taps are floats [2t+3 .. 2t+14]; read 7 aligned b64 [2t+2 .. 2t+15].
template <int S>
__device__ __forceinline__ void hblur_slot(Rings& rg, float (*lds)[2][LDSW],
                                           const float* wv, int t)
{
  const v2f* xb = (const v2f*)lds[S][0];
  const v2f* yb = (const v2f*)lds[S][1];
  v2f X[7], Y[7];
  #pragma unroll
  for (int j = 0; j < 7; ++j) { X[j] = xb[t + 1 + j]; Y[j] = yb[t + 1 + j]; }

  v2f hx = {0.f,0.f}, hy = {0.f,0.f}, hx2 = {0.f,0.f}, hy2 = {0.f,0.f}, hxy = {0.f,0.f};
  #pragma unroll
  for (int k = 0; k < KW; ++k) {
    v2f xt, yt;
    if (k & 1) { xt = X[(k + 1) >> 1]; yt = Y[(k + 1) >> 1]; }
    else {
      xt.x = X[k >> 1].y; xt.y = X[(k >> 1) + 1].x;
      yt.x = Y[k >> 1].y; yt.y = Y[(k >> 1) + 1].x;
    }
    const float w = wv[k];
    const v2f tt = w * xt, uu = w * yt;
    hx += tt; hy += uu;
    hx2 = __builtin_elementwise_fma(tt, xt, hx2);
    hy2 = __builtin_elementwise_fma(uu, yt, hy2);
    hxy = __builtin_elementwise_fma(tt, yt, hxy);
  }
  rg.hx[S] = hx; rg.hy[S] = hy; rg.hx2[S] = hx2; rg.hy2[S] = hy2; rg.hxy[S] = hxy;
}

// steady-state phase P: issue replacement-row loads, hblur LDS slot (P+10)%11
// into ring slot (P+10)%11, vertical blur + SSIM epilogue, then overwrite the
// just-consumed LDS slot with the replacement row (antidependence keeps order).
template <int P, bool STG>
__device__ __forceinline__ void phase_step(Rings& rg, float (*lds)[2][LDSW],
                                           const float* wv, int t, v2f& acc,
                                           const float* __restrict__ xp,
                                           const float* __restrict__ yp,
                                           int C0, int riRep)
{
  constexpr int S = (P + 2 * HALO) % KW;
  Staged st;
  if (STG) st = stage_issue(xp, yp, C0, riRep, t);

  hblur_slot<S>(rg, lds, wv, t);

  v2f mx = {0.f,0.f}, my = {0.f,0.f}, ex2 = {0.f,0.f}, ey2 = {0.f,0.f}, exy = {0.f,0.f};
  #pragma unroll
  for (int k = 0; k < KW; ++k) {
    const int s = (P + k) % KW;   // constant after unroll
    const float w = wv[k];
    mx  = __builtin_elementwise_fma((v2f)(w), rg.hx[s],  mx);
    my  = __builtin_elementwise_fma((v2f)(w), rg.hy[s],  my);
    ex2 = __builtin_elementwise_fma((v2f)(w), rg.hx2[s], ex2);
    ey2 = __builtin_elementwise_fma((v2f)(w), rg.hy2[s], ey2);
    exy = __builtin_elementwise_fma((v2f)(w), rg.hxy[s], exy);
  }
  const v2f mx2 = mx * mx, my2 = my * my, mxy = mx * my;
  const v2f sx2 = ex2 - mx2, sy2 = ey2 - my2, sxy = exy - mxy;
  const v2f num = (2.f * mxy + C1V) * (2.f * sxy + C2V);
  const v2f den = (mx2 + my2 + C1V) * (sx2 + sy2 + C2V) + EPSV;
  v2f r;
  r.x = __builtin_amdgcn_rcpf(den.x);
  r.y = __builtin_amdgcn_rcpf(den.y);
  acc = __builtin_elementwise_fma(num, r, acc);

  if (STG) stage_commit(lds, S, st, t);
}

// prologue phase J: hblur slot J into ring slot J, replace slot J with row R0+6+J
template <int J>
__device__ __forceinline__ void pro_phase(Rings& rg, float (*lds)[2][LDSW],
                                          const float* wv, int t,
                                          const float* __restrict__ xp,
                                          const float* __restrict__ yp,
                                          int C0, int riRep)
{
  Staged st = stage_issue(xp, yp, C0, riRep, t);
  hblur_slot<J>(rg, lds, wv, t);
  stage_commit(lds, J, st, t);
}

__global__ __launch_bounds__(BLOCK, 2) void ssim_main(const float* __restrict__ x,
                                                      const float* __restrict__ y,
                                                      float* __restrict__ partial)
{
  __shared__ float lds[KW][2][LDSW];

  const int t = threadIdx.x;
  const int plane = blockIdx.y;
  const int colT = blockIdx.x & (COL_TILES - 1);
  const int rowT = blockIdx.x >> 2;
  const int C0 = colT * COLS_PB;
  const int R0 = rowT * ROWS_PB;

  const float* xp = x + (ptrdiff_t)plane * (HH * WW);
  const float* yp = y + (ptrdiff_t)plane * (HH * WW);

  // Gaussian window (exact reference formula), hoisted to SGPRs.
  float wv[KW];
  {
    float s = 0.f;
    #pragma unroll
    for (int k = 0; k < KW; ++k) {
      const float d = (float)(k - HALO);
      wv[k] = expf(-(d * d) / 4.5f);   // 2*sigma^2 = 4.5
      s += wv[k];
    }
    const float inv = 1.f / s;
    #pragma unroll
    for (int k = 0; k < KW; ++k) {
      wv[k] *= inv;
      wv[k] = __int_as_float(__builtin_amdgcn_readfirstlane(__float_as_int(wv[k])));
    }
  }

  Rings rg;
  v2f acc = {0.f, 0.f};

  // initial staging: rows R0-5 .. R0+5 -> slots 0..10
  for (int r = 0; r < KW; ++r) {
    Staged st = stage_issue(xp, yp, C0, R0 - HALO + r, t);
    stage_commit(lds, r, st, t);
  }
  __syncthreads();

  // prologue: fill ring slots 0..9; each replaces its slot with row R0+6+J
  pro_phase<0>(rg, lds, wv, t, xp, yp, C0, R0 + 6 + 0);
  pro_phase<1>(rg, lds, wv, t, xp, yp, C0, R0 + 6 + 1);
  pro_phase<2>(rg, lds, wv, t, xp, yp, C0, R0 + 6 + 2);
  pro_phase<3>(rg, lds, wv, t, xp, yp, C0, R0 + 6 + 3);
  pro_phase<4>(rg, lds, wv, t, xp, yp, C0, R0 + 6 + 4);
  pro_phase<5>(rg, lds, wv, t, xp, yp, C0, R0 + 6 + 5);
  pro_phase<6>(rg, lds, wv, t, xp, yp, C0, R0 + 6 + 6);
  pro_phase<7>(rg, lds, wv, t, xp, yp, C0, R0 + 6 + 7);
  pro_phase<8>(rg, lds, wv, t, xp, yp, C0, R0 + 6 + 8);
  pro_phase<9>(rg, lds, wv, t, xp, yp, C0, R0 + 6 + 9);

  // main loop: 5 groups x 11 output rows; group g phase P consumes raw row
  // R0+5+11g+P (slot (P+10)%11) and stages row R0+16+11g+P into that slot.
  #pragma unroll 1
  for (int g = 0; g < NGRP; ++g) {
    const int rb = R0 + 16 + 11 * g;
    phase_step<0,  true>(rg, lds, wv, t, acc, xp, yp, C0, rb + 0);
    phase_step<1,  true>(rg, lds, wv, t, acc, xp, yp, C0, rb + 1);
    phase_step<2,  true>(rg, lds, wv, t, acc, xp, yp, C0, rb + 2);
    phase_step<3,  true>(rg, lds, wv, t, acc, xp, yp, C0, rb + 3);
    phase_step<4,  true>(rg, lds, wv, t, acc, xp, yp, C0, rb + 4);
    phase_step<5,  true>(rg, lds, wv, t, acc, xp, yp, C0, rb + 5);
    phase_step<6,  true>(rg, lds, wv, t, acc, xp, yp, C0, rb + 6);
    phase_step<7,  true>(rg, lds, wv, t, acc, xp, yp, C0, rb + 7);
    phase_step<8,  true>(rg, lds, wv, t, acc, xp, yp, C0, rb + 8);
    phase_step<9,  true>(rg, lds, wv, t, acc, xp, yp, C0, rb + 9);
    phase_step<10, true>(rg, lds, wv, t, acc, xp, yp, C0, rb + 10);
  }
  // remainder: 9 output rows, no staging (rows were staged by group 4)
  phase_step<0, false>(rg, lds, wv, t, acc, xp, yp, C0, 0);
  phase_step<1, false>(rg, lds, wv, t, acc, xp, yp, C0, 0);
  phase_step<2, false>(rg, lds, wv, t, acc, xp, yp, C0, 0);
  phase_step<3, false>(rg, lds, wv, t, acc, xp, yp, C0, 0);
  phase_step<4, false>(rg, lds, wv, t, acc, xp, yp, C0, 0);
  phase_step<5, false>(rg, lds, wv, t, acc, xp, yp, C0, 0);
  phase_step<6, false>(rg, lds, wv, t, acc, xp, yp, C0, 0);
  phase_step<7, false>(rg, lds, wv, t, acc, xp, yp, C0, 0);
  phase_step<8, false>(rg, lds, wv, t, acc, xp, yp, C0, 0);

  // single-wave block: shuffle reduce, one atomic per block
  float a = acc.x + acc.y;
  #pragma unroll
  for (int off = 32; off > 0; off >>= 1) a += __shfl_down(a, off);
  if (t == 0) atomicAdd(partial, a);
}

__global__ void zero_ws_kernel(float* __restrict__ ws) { ws[0] = 0.f; }

__global__ void finalize_kernel(const float* __restrict__ ws, float* __restrict__ out)
{
  out[0] = 1.f - ws[0] * (1.f / NPIX);
}

extern "C" void kernel_launch(void* const* d_in, const int* in_sizes, int n_in,
                              void* d_out, int out_size, void* d_ws, size_t ws_size,
                              hipStream_t stream)
{
  const float* x = (const float*)d_in[0];
  const float* y = (const float*)d_in[1];
  float* ws = (float*)d_ws;
  float* out = (float*)d_out;

  hipLaunchKernelGGL(zero_ws_kernel, dim3(1), dim3(1), 0, stream, ws);
  dim3 grid(COL_TILES * ROW_TILES, NPLANES);
  hipLaunchKernelGGL(ssim_main, grid, dim3(BLOCK), 0, stream, x, y, ws);
  hipLaunchKernelGGL(finalize_kernel, dim3(1), dim3(1), 0, stream, ws, out);
}